// Round 5
// baseline (410.833 us; speedup 1.0000x reference)
//
#include <hip/hip_runtime.h>
#include <hip/hip_fp16.h>
#include <type_traits>

#define NEG_SLOPE 0.2f
#define BKT_SHIFT 8
#define BKT_SIZE (1 << BKT_SHIFT)     // 256 dst nodes per bucket
#define P1_EPT 16                     // edges per thread in edge-pass kernels

typedef __attribute__((ext_vector_type(8))) short short8;
typedef __attribute__((ext_vector_type(4))) float float4v;

__device__ inline int rfl_i(int v) { return __builtin_amdgcn_readfirstlane(v); }

// round-to-nearest-even fp32 -> bf16
__device__ inline unsigned short f2bf(float f) {
    unsigned u = __float_as_uint(f);
    unsigned r = u + 0x7FFFu + ((u >> 16) & 1u);
    return (unsigned short)(r >> 16);
}
__device__ inline float bf2f(unsigned short b) {
    return __uint_as_float(((unsigned)b) << 16);
}

// ---------------- CSR build, atomic 2-pass (no arena) ----------------
// K1 body: per-dst histogram (global atomics over 400KB L2-resident table)
// + LDS-reduced per-bucket totals -> gbkt (391 atomics/block, not 4096).
__device__ __forceinline__ void hist_body(
        const int* __restrict__ dst, int e,
        int* __restrict__ hist, int* __restrict__ gbkt, int nbkt, int b_id,
        char* smem) {
    int (*cnt)[392] = (int(*)[392])smem;
    int t = threadIdx.x;
    int wv = t >> 6;
    int cb = b_id * (256 * P1_EPT);
    for (int i = t; i < 4 * 392; i += 256) ((int*)cnt)[i] = 0;
    __syncthreads();
#pragma unroll
    for (int i4 = 0; i4 < P1_EPT / 4; ++i4) {
        int eid0 = cb + (i4 * 256 + t) * 4;
        int4 d4;
        bool full = (eid0 + 3 < e);
        if (full) d4 = *(const int4*)(dst + eid0);
#pragma unroll
        for (int j = 0; j < 4; ++j) {
            int eid = eid0 + j;
            int d;
            if (full) d = (&d4.x)[j];
            else if (eid < e) d = dst[eid];
            else continue;
            atomicAdd(&hist[d], 1);
            atomicAdd(&cnt[wv][d >> BKT_SHIFT], 1);
        }
    }
    __syncthreads();
    for (int b = t; b < nbkt; b += 256) {
        int tot = cnt[0][b] + cnt[1][b] + cnt[2][b] + cnt[3][b];
        if (tot > 0) atomicAdd(&gbkt[b], tot);
    }
}

// K2: per bucket (256 dst): inter-bucket base (reduce gbkt[<b]) + intra-bucket
// scan of hist slice -> row_off + cur (scatter cursors). One kernel, no serial pass.
__global__ __launch_bounds__(256) void scan_kernel(
        const int* __restrict__ hist, const int* __restrict__ gbkt,
        int* __restrict__ row_off, int* __restrict__ cur,
        int n, int e_total, int nbkt) {
    __shared__ int tmp[256];
    int b = blockIdx.x, t = threadIdx.x;
    // bbase = sum of gbkt[0..b)
    int i1 = 256 + t;
    int v0 = (t < b) ? gbkt[t] : 0;
    int v1 = (i1 < b) ? gbkt[i1] : 0;
    tmp[t] = v0 + v1;
    __syncthreads();
    for (int o = 128; o > 0; o >>= 1) {
        if (t < o) tmp[t] += tmp[t + o];
        __syncthreads();
    }
    int bbase_b = tmp[0];
    __syncthreads();

    int d0 = b << BKT_SHIFT;
    int nloc = min(BKT_SIZE, n - d0);
    int c = (t < nloc) ? hist[d0 + t] : 0;
    tmp[t] = c;
    __syncthreads();
    for (int o = 1; o < 256; o <<= 1) {
        int x = tmp[t];
        int y = (t >= o) ? tmp[t - o] : 0;
        __syncthreads();
        tmp[t] = x + y;
        __syncthreads();
    }
    int pos0 = bbase_b + tmp[t] - c;
    if (t < nloc) {
        row_off[d0 + t] = pos0;
        cur[d0 + t] = pos0;
    }
    if (b == nbkt - 1 && t == 0) row_off[n] = e_total;
}

// K3: scatter edges into CSR slots via per-dst cursor atomics.
// cur table 400KB (L2-resident); csr windows per dst are L2-local too.
__global__ __launch_bounds__(256) void scatter_kernel(
        const int* __restrict__ src, const int* __restrict__ dst, int e,
        int* __restrict__ cur, int* __restrict__ csr_src) {
    int t = threadIdx.x;
    int cb = (int)blockIdx.x * (256 * P1_EPT);
#pragma unroll
    for (int i4 = 0; i4 < P1_EPT / 4; ++i4) {
        int eid0 = cb + (i4 * 256 + t) * 4;
        int4 s4, d4;
        bool full = (eid0 + 3 < e);
        if (full) {
            s4 = *(const int4*)(src + eid0);
            d4 = *(const int4*)(dst + eid0);
        }
#pragma unroll
        for (int j = 0; j < 4; ++j) {
            int eid = eid0 + j;
            int s, d;
            if (full) {
                s = (&s4.x)[j];
                d = (&d4.x)[j];
            } else if (eid < e) {
                s = src[eid];
                d = dst[eid];
            } else {
                continue;
            }
            int pos = atomicAdd(&cur[d], 1);
            csr_src[pos] = s;
        }
    }
}

// ---------------- MFMA GEMM body (in-kernel W decomposition) ----------------
// h[N,64] row-major = x[N,K] @ W[K,64] via v_mfma_f32_16x16x32_bf16, bf16x3.
// IN = float (layer1) or __half (layer2).
template <int KT, typename IN>
__device__ __forceinline__ void gemm_body(
        const IN* __restrict__ x, const float* __restrict__ W,
        const float* __restrict__ al, const float* __restrict__ ar,
        __half* __restrict__ h16, float* __restrict__ el,
        float* __restrict__ er, int n, int bid, int nblocks, char* smem) {
    constexpr int K = KT * 32;
    constexpr int WFRAG = KT * 4 * 64 * 8;   // shorts
    unsigned short* Wh = (unsigned short*)smem;
    unsigned short* Wl = Wh + WFRAG;
    for (int idx = threadIdx.x; idx < KT * 4 * 64; idx += 256) {
        int lane = idx & 63, fbkt = idx >> 6;
        int fb = fbkt & 3, kt = fbkt >> 2;
        int q = lane >> 4, c = lane & 15;
#pragma unroll
        for (int j = 0; j < 8; ++j) {
            float w = W[(kt * 32 + q * 8 + j) * 64 + fb * 16 + c];
            unsigned short hi = f2bf(w);
            Wh[idx * 8 + j] = hi;
            Wl[idx * 8 + j] = f2bf(w - bf2f(hi));
        }
    }
    __syncthreads();

    int lane = threadIdx.x & 63;
    int q = lane >> 4, c = lane & 15;
    int wave = bid * 4 + (int)(threadIdx.x >> 6);
    int nwaves = nblocks * 4;
    int ntiles = (n + 15) >> 4;

    float alv[4], arv[4];
#pragma unroll
    for (int fb = 0; fb < 4; ++fb) {
        alv[fb] = al[fb * 16 + c];
        arv[fb] = ar[fb * 16 + c];
    }

    for (int t = wave; t < ntiles; t += nwaves) {
        int v0 = t * 16;
        int row = min(v0 + c, n - 1);
        const IN* xr = x + (size_t)row * K + q * 8;

        short8 Ah[KT], Al[KT];
#pragma unroll
        for (int kt = 0; kt < KT; ++kt) {
            float xv[8];
            if constexpr (std::is_same<IN, float>::value) {
                *(float4*)&xv[0] = *(const float4*)(xr + kt * 32);
                *(float4*)&xv[4] = *(const float4*)(xr + kt * 32 + 4);
            } else {
                __half hh[8];
                *(uint4*)hh = *(const uint4*)(xr + kt * 32);
#pragma unroll
                for (int j = 0; j < 8; ++j) xv[j] = __half2float(hh[j]);
            }
#pragma unroll
            for (int j = 0; j < 8; ++j) {
                unsigned short hi = f2bf(xv[j]);
                Ah[kt][j] = (short)hi;
                Al[kt][j] = (short)f2bf(xv[j] - bf2f(hi));
            }
        }

        float4v acc[4];
#pragma unroll
        for (int fb = 0; fb < 4; ++fb) acc[fb] = (float4v)0.f;

#pragma unroll
        for (int kt = 0; kt < KT; ++kt) {
#pragma unroll
            for (int fb = 0; fb < 4; ++fb) {
                short8 bh = *(const short8*)&Wh[((kt * 4 + fb) * 64 + lane) * 8];
                short8 bl = *(const short8*)&Wl[((kt * 4 + fb) * 64 + lane) * 8];
                acc[fb] = __builtin_amdgcn_mfma_f32_16x16x32_bf16(Ah[kt], bh, acc[fb], 0, 0, 0);
                acc[fb] = __builtin_amdgcn_mfma_f32_16x16x32_bf16(Al[kt], bh, acc[fb], 0, 0, 0);
                acc[fb] = __builtin_amdgcn_mfma_f32_16x16x32_bf16(Ah[kt], bl, acc[fb], 0, 0, 0);
            }
        }

#pragma unroll
        for (int r = 0; r < 4; ++r) {
            int v = v0 + q * 4 + r;
            float pl = 0.f, pr = 0.f;
            bool ok = (v < n);
#pragma unroll
            for (int fb = 0; fb < 4; ++fb) {
                float hv = acc[fb][r];
                if (ok) h16[(size_t)v * 64 + fb * 16 + c] = __float2half(hv);
                pl = fmaf(hv, alv[fb], pl);
                pr = fmaf(hv, arv[fb], pr);
            }
#pragma unroll
            for (int off = 8; off > 0; off >>= 1) {
                pl += __shfl_xor(pl, off);
                pr += __shfl_xor(pr, off);
            }
            if (ok && c == 0) { el[v] = pl; er[v] = pr; }
        }
    }
}

// fused: blocks [0,npb) = histogram pass, [npb, grid) = gemm layer1.
// Disjoint memory: hist writes hist/gbkt; gemm writes h16/el/er.
__global__ __launch_bounds__(256) void hist_gemm1(
        const int* __restrict__ dst, int e,
        int* __restrict__ hist, int* __restrict__ gbkt, int nbkt, int npb,
        const float* __restrict__ x, const float* __restrict__ W1,
        const float* __restrict__ al, const float* __restrict__ ar,
        __half* __restrict__ h16, float* __restrict__ el,
        float* __restrict__ er, int n) {
    __shared__ char smem[32768];   // max(hist 6.3KB, gemm KT=4 32KB)
    int b = (int)blockIdx.x;
    if (b < npb)
        hist_body(dst, e, hist, gbkt, nbkt, b, smem);
    else
        gemm_body<4, float>(x, W1, al, ar, h16, el, er, n, b - npb,
                            (int)gridDim.x - npb, smem);
}

template <int KT, typename IN>
__global__ __launch_bounds__(256) void gemm_mfma_kernel(
        const IN* __restrict__ x, const float* __restrict__ W,
        const float* __restrict__ al, const float* __restrict__ ar,
        __half* __restrict__ h16, float* __restrict__ el,
        float* __restrict__ er, int n) {
    __shared__ char smem[KT * 4 * 64 * 8 * 2 * 2];
    gemm_body<KT, IN>(x, W, al, ar, h16, el, er, n, (int)blockIdx.x,
                      (int)gridDim.x, smem);
}

// ---------------- softmax-aggregate (round-0 proven form) ----------------
// 1 node/wave; 4 edges per step (16-lane groups, uint2 = 4 fp16 feats/lane).
// OUT = __half (layer1: relu'd hr) or float (layer2: d_out).
template <typename OUT>
__global__ __launch_bounds__(256) void agg_kernel(
        const int* __restrict__ row_off, const int* __restrict__ csr_src,
        const __half* __restrict__ h16, const float* __restrict__ el,
        const float* __restrict__ er, const float* __restrict__ bias,
        OUT* __restrict__ out, int n, int do_relu) {
    int lane = threadIdx.x & 63;
    int grp = lane >> 4;      // 0..3: edge slot within a 4-edge step
    int c = lane & 15;        // feature quad: features 4c..4c+3
    int gwave = rfl_i((int)((blockIdx.x * blockDim.x + threadIdx.x) >> 6));
    int nwaves = (gridDim.x * blockDim.x) >> 6;
    float4 b4 = ((const float4*)bias)[c];
    for (int v = gwave; v < n; v += nwaves) {
        int rs = rfl_i(row_off[v]), re = rfl_i(row_off[v + 1]);
        float er_v = er[v];
        float a0 = 0.f, a1 = 0.f, a2 = 0.f, a3 = 0.f, ssum = 0.f;
        for (int base = rs; base < re; base += 64) {
            int cnt = min(64, re - base);
            int s_e = 0;
            float ex = 0.f;
            if (lane < cnt) {
                s_e = csr_src[base + lane];
                float ev = el[s_e] + er_v;
                ev = (ev >= 0.f) ? ev : NEG_SLOPE * ev;
                ex = __expf(ev);
            }
            float cs = ex;
#pragma unroll
            for (int off = 32; off > 0; off >>= 1) cs += __shfl_xor(cs, off);
            ssum += cs;
            int cnt16 = (cnt + 15) & ~15;
            for (int j = 0; j < cnt16; j += 16) {
                int sj[4];
                float exj[4];
                uint2 hv[4];
#pragma unroll
                for (int u = 0; u < 4; ++u) {
                    int idx = j + 4 * u + grp;
                    sj[u] = __shfl(s_e, idx);
                    exj[u] = __shfl(ex, idx);
                    hv[u] = *((const uint2*)(h16 + (size_t)sj[u] * 64) + c);
                }
#pragma unroll
                for (int u = 0; u < 4; ++u) {
                    float2 f01 = __half22float2(*(__half2*)&hv[u].x);
                    float2 f23 = __half22float2(*(__half2*)&hv[u].y);
                    a0 = fmaf(exj[u], f01.x, a0);
                    a1 = fmaf(exj[u], f01.y, a1);
                    a2 = fmaf(exj[u], f23.x, a2);
                    a3 = fmaf(exj[u], f23.y, a3);
                }
            }
        }
        // combine the 4 edge-groups: reduce over lane bits 4,5
#pragma unroll
        for (int off = 16; off < 64; off <<= 1) {
            a0 += __shfl_xor(a0, off);
            a1 += __shfl_xor(a1, off);
            a2 += __shfl_xor(a2, off);
            a3 += __shfl_xor(a3, off);
        }
        if (lane < 16) {
            float4 o;
            if (re > rs) {
                float inv = 1.0f / ssum;
                o.x = fmaf(a0, inv, b4.x);
                o.y = fmaf(a1, inv, b4.y);
                o.z = fmaf(a2, inv, b4.z);
                o.w = fmaf(a3, inv, b4.w);
            } else {
                o = b4;
            }
            if (do_relu) {
                o.x = fmaxf(o.x, 0.f);
                o.y = fmaxf(o.y, 0.f);
                o.z = fmaxf(o.z, 0.f);
                o.w = fmaxf(o.w, 0.f);
            }
            if constexpr (std::is_same<OUT, __half>::value) {
                uint2 pk;
                *(__half2*)&pk.x = __float22half2_rn(make_float2(o.x, o.y));
                *(__half2*)&pk.y = __float22half2_rn(make_float2(o.z, o.w));
                ((uint2*)(out + (size_t)v * 64))[c] = pk;
            } else {
                ((float4*)(out + (size_t)v * 64))[c] = o;
            }
        }
    }
}

extern "C" void kernel_launch(void* const* d_in, const int* in_sizes, int n_in,
                              void* d_out, int out_size, void* d_ws, size_t ws_size,
                              hipStream_t stream) {
    (void)n_in; (void)out_size; (void)ws_size;
    const float* features = (const float*)d_in[0];
    // d_in[1] = edge_weights, unused by the reference forward
    const int*   src = (const int*)d_in[2];
    const int*   dst = (const int*)d_in[3];
    const float* W1  = (const float*)d_in[4];
    const float* al1 = (const float*)d_in[5];
    const float* ar1 = (const float*)d_in[6];
    const float* b1  = (const float*)d_in[7];
    const float* W2  = (const float*)d_in[8];
    const float* al2 = (const float*)d_in[9];
    const float* ar2 = (const float*)d_in[10];
    const float* b2  = (const float*)d_in[11];

    const int n = in_sizes[0] / 128;   // 100000
    const int e = in_sizes[2];         // 1600000
    float* out = (float*)d_out;

    char* p = (char*)d_ws;
    auto alloc = [&](size_t bytes) -> char* {
        char* q = p;
        p += (bytes + 255) & ~(size_t)255;
        return q;
    };
    int*    row_off = (int*)alloc((size_t)(n + 1) * 4);
    int*    csr_src = (int*)alloc((size_t)e * 4);
    __half* h16     = (__half*)alloc((size_t)n * 64 * 2);
    __half* hr      = (__half*)alloc((size_t)n * 64 * 2);
    float*  el      = (float*)alloc((size_t)n * 4);
    float*  er      = (float*)alloc((size_t)n * 4);
    int*    hist    = (int*)alloc((size_t)(n + 512) * 4);   // hist[n] ++ gbkt[512]
    int*    gbkt    = hist + n;
    int*    cur     = (int*)alloc((size_t)n * 4);

    const int nbkt = (n + BKT_SIZE - 1) >> BKT_SHIFT;            // 391
    const int npb  = (e + 256 * P1_EPT - 1) / (256 * P1_EPT);    // 391

    // zero hist + gbkt in one small memset (L2-resident, ~2us)
    hipMemsetAsync(hist, 0, (size_t)(n + 512) * 4, stream);

    // K1: dst histogram (global atomics) runs concurrently with gemm1
    hist_gemm1<<<npb + 512, 256, 0, stream>>>(dst, e, hist, gbkt, nbkt, npb,
                                              features, W1, al1, ar1, h16, el, er, n);
    // K2: row_off + scatter cursors (fused inter/intra-bucket scan)
    scan_kernel<<<nbkt, 256, 0, stream>>>(hist, gbkt, row_off, cur, n, e, nbkt);
    // K3: scatter edges into CSR
    scatter_kernel<<<npb, 256, 0, stream>>>(src, dst, e, cur, csr_src);

    // layer 1 aggregate
    agg_kernel<__half><<<4096, 256, 0, stream>>>(row_off, csr_src, h16, el, er, b1, hr, n, 1);

    // layer 2
    gemm_mfma_kernel<2, __half><<<512, 256, 0, stream>>>(hr, W2, al2, ar2, h16, el, er, n);
    agg_kernel<float><<<4096, 256, 0, stream>>>(row_off, csr_src, h16, el, er, b2, out, n, 0);
}

// Round 6
// 310.274 us; speedup vs baseline: 1.3241x; 1.3241x over previous
//
#include <hip/hip_runtime.h>
#include <hip/hip_fp16.h>
#include <type_traits>

#define NEG_SLOPE 0.2f
#define BKT_SHIFT 8
#define BKT_SIZE (1 << BKT_SHIFT)   // 256 dst nodes per bucket
#define NPB_PAD 400                 // padded partition-block count (npb=391)
#define SCAP 96                     // arena slots per (bucket, block); mean 10.5
#define BCAP 6144                   // csr window per bucket; mean 4096, +32 sigma
#define P1_EPT 16                   // edges per thread in partition pass

typedef __attribute__((ext_vector_type(8))) short short8;
typedef __attribute__((ext_vector_type(4))) float float4v;

__device__ inline int rfl_i(int v) { return __builtin_amdgcn_readfirstlane(v); }

// round-to-nearest-even fp32 -> bf16
__device__ inline unsigned short f2bf(float f) {
    unsigned u = __float_as_uint(f);
    unsigned r = u + 0x7FFFu + ((u >> 16) & 1u);
    return (unsigned short)(r >> 16);
}
__device__ inline float bf2f(unsigned short b) {
    return __uint_as_float(((unsigned)b) << 16);
}

// ---------------- partition body: fixed (bucket, block) arena slots ----------------
// NO global atomics, NO init required: every cnts2[b][blk] is overwritten.
// Record packed to 4B: src<<8 | (dst & 255)   (src < 2^17 -> 25 bits).
__device__ __forceinline__ void partition_body(
        const int* __restrict__ src, const int* __restrict__ dst, int e,
        int* __restrict__ part, int* __restrict__ cnts2, int nbkt, int npb,
        int blk, char* smem) {
    int (*cnt)[392]    = (int(*)[392])smem;
    int (*base_l)[392] = (int(*)[392])(smem + 4 * 392 * sizeof(int));
    int t = threadIdx.x;
    int wv = t >> 6;
    int cb = blk * (256 * P1_EPT);
    for (int i = t; i < 4 * 392; i += 256) ((int*)cnt)[i] = 0;
    __syncthreads();
    int sr[P1_EPT], ds[P1_EPT], rk[P1_EPT];
#pragma unroll
    for (int i4 = 0; i4 < P1_EPT / 4; ++i4) {
        int eid0 = cb + (i4 * 256 + t) * 4;
        int4 s4, d4;
        bool full = (eid0 + 3 < e);
        if (full) {
            s4 = *(const int4*)(src + eid0);
            d4 = *(const int4*)(dst + eid0);
        }
#pragma unroll
        for (int j = 0; j < 4; ++j) {
            int i = i4 * 4 + j;
            int eid = eid0 + j;
            if (full) {
                sr[i] = (&s4.x)[j];
                ds[i] = (&d4.x)[j];
            } else if (eid < e) {
                sr[i] = src[eid];
                ds[i] = dst[eid];
            }
            rk[i] = (eid < e) ? atomicAdd(&cnt[wv][ds[i] >> BKT_SHIFT], 1) : -1;
        }
    }
    __syncthreads();
    // per-bucket wave prefixes (offset within this block's fixed slot) + count
    for (int b = t; b < nbkt; b += 256) {
        int c0 = cnt[0][b], c1 = cnt[1][b], c2 = cnt[2][b], c3 = cnt[3][b];
        int tot = c0 + c1 + c2 + c3;
        base_l[0][b] = 0;
        base_l[1][b] = c0;
        base_l[2][b] = c0 + c1;
        base_l[3][b] = c0 + c1 + c2;
        cnts2[b * NPB_PAD + blk] = min(tot, SCAP);   // ALWAYS write (no init)
    }
    __syncthreads();
#pragma unroll
    for (int i = 0; i < P1_EPT; ++i) {
        if (rk[i] >= 0) {
            int b = ds[i] >> BKT_SHIFT;
            int o = base_l[wv][b] + rk[i];
            if (o < SCAP)   // safety clamp (P ~ 0)
                part[((size_t)b * NPB_PAD + blk) * SCAP + o] =
                    (sr[i] << BKT_SHIFT) | (ds[i] & (BKT_SIZE - 1));
        }
    }
}

// ---------------- finesort4: bucket-independent, LDS-staged, atomic-free io ----------------
// Bucket b owns csr window [b*BCAP, ...). Stages its ~4096 records into LDS
// once, counts, scans, writes row_beg/row_end and scatters (all LDS-local
// except the coalesced-window csr writes). No cross-bucket dependency.
__global__ __launch_bounds__(256) void finesort4(
        const int* __restrict__ part, const int* __restrict__ cnts2,
        int* __restrict__ row_beg, int* __restrict__ row_end,
        int* __restrict__ csr_src, int n, int nbkt, int npb) {
    __shared__ int cnt[256];
    __shared__ int cur[256];
    __shared__ int tmp[256];
    __shared__ int stage[BCAP];   // 24KB
    int b = blockIdx.x, t = threadIdx.x;
    // per-partition-block counts for blks 2t, 2t+1 -> exclusive prefix
    int blk0 = 2 * t, blk1 = 2 * t + 1;
    int c0 = (blk0 < npb) ? cnts2[b * NPB_PAD + blk0] : 0;
    int c1 = (blk1 < npb) ? cnts2[b * NPB_PAD + blk1] : 0;
    int s = c0 + c1;
    tmp[t] = s;
    __syncthreads();
    for (int o = 1; o < 256; o <<= 1) {
        int x = tmp[t];
        int y = (t >= o) ? tmp[t - o] : 0;
        __syncthreads();
        tmp[t] = x + y;
        __syncthreads();
    }
    int excl = tmp[t] - s;
    int S = tmp[255];
    int Seff = min(S, BCAP);
    // stage the two runs this thread owns
    {
        const int* sp0 = part + ((size_t)b * NPB_PAD + blk0) * SCAP;
        for (int i = 0; i < c0; ++i) {
            int p = excl + i;
            if (p < BCAP) stage[p] = sp0[i];
        }
        const int* sp1 = part + ((size_t)b * NPB_PAD + blk1) * SCAP;
        int sb1 = excl + c0;
        for (int i = 0; i < c1; ++i) {
            int p = sb1 + i;
            if (p < BCAP) stage[p] = sp1[i];
        }
    }
    cnt[t] = 0;
    __syncthreads();   // fences stage writes + cnt zeroing
    for (int i = t; i < Seff; i += 256)
        atomicAdd(&cnt[stage[i] & (BKT_SIZE - 1)], 1);
    __syncthreads();
    int d0 = b << BKT_SHIFT;
    int nloc = min(BKT_SIZE, n - d0);
    int c = cnt[t];
    tmp[t] = c;
    __syncthreads();
    for (int o = 1; o < 256; o <<= 1) {
        int x = tmp[t];
        int y = (t >= o) ? tmp[t - o] : 0;
        __syncthreads();
        tmp[t] = x + y;
        __syncthreads();
    }
    int pos0 = b * BCAP + tmp[t] - c;
    cur[t] = pos0;
    if (t < nloc) {
        row_beg[d0 + t] = pos0;
        row_end[d0 + t] = pos0 + c;
    }
    __syncthreads();
    for (int i = t; i < Seff; i += 256) {
        int pk = stage[i];
        int pos = atomicAdd(&cur[pk & (BKT_SIZE - 1)], 1);
        csr_src[pos] = ((unsigned)pk) >> BKT_SHIFT;
    }
}

// ---------------- MFMA GEMM body (layer 1; in-kernel W decomposition) ----------------
// h16[N,64] fp16 row-major = x[N,128] @ W1[128,64] via mfma_f32_16x16x32_bf16,
// bf16x3 split; also el/er attention dots.
__device__ __forceinline__ void gemm_body(
        const float* __restrict__ x, const float* __restrict__ W,
        const float* __restrict__ al, const float* __restrict__ ar,
        __half* __restrict__ h16, float* __restrict__ el,
        float* __restrict__ er, int n, int bid, int nblocks, char* smem) {
    constexpr int KT = 4;
    constexpr int K = KT * 32;
    constexpr int WFRAG = KT * 4 * 64 * 8;   // shorts
    unsigned short* Wh = (unsigned short*)smem;
    unsigned short* Wl = Wh + WFRAG;
    for (int idx = threadIdx.x; idx < KT * 4 * 64; idx += 256) {
        int lane = idx & 63, fbkt = idx >> 6;
        int fb = fbkt & 3, kt = fbkt >> 2;
        int q = lane >> 4, c = lane & 15;
#pragma unroll
        for (int j = 0; j < 8; ++j) {
            float w = W[(kt * 32 + q * 8 + j) * 64 + fb * 16 + c];
            unsigned short hi = f2bf(w);
            Wh[idx * 8 + j] = hi;
            Wl[idx * 8 + j] = f2bf(w - bf2f(hi));
        }
    }
    __syncthreads();

    int lane = threadIdx.x & 63;
    int q = lane >> 4, c = lane & 15;
    int wave = bid * 4 + (int)(threadIdx.x >> 6);
    int nwaves = nblocks * 4;
    int ntiles = (n + 15) >> 4;

    float alv[4], arv[4];
#pragma unroll
    for (int fb = 0; fb < 4; ++fb) {
        alv[fb] = al[fb * 16 + c];
        arv[fb] = ar[fb * 16 + c];
    }

    for (int t = wave; t < ntiles; t += nwaves) {
        int v0 = t * 16;
        int row = min(v0 + c, n - 1);
        const float* xr = x + (size_t)row * K + q * 8;

        short8 Ah[KT], Al[KT];
#pragma unroll
        for (int kt = 0; kt < KT; ++kt) {
            float xv[8];
            *(float4*)&xv[0] = *(const float4*)(xr + kt * 32);
            *(float4*)&xv[4] = *(const float4*)(xr + kt * 32 + 4);
#pragma unroll
            for (int j = 0; j < 8; ++j) {
                unsigned short hi = f2bf(xv[j]);
                Ah[kt][j] = (short)hi;
                Al[kt][j] = (short)f2bf(xv[j] - bf2f(hi));
            }
        }

        float4v acc[4];
#pragma unroll
        for (int fb = 0; fb < 4; ++fb) acc[fb] = (float4v)0.f;

#pragma unroll
        for (int kt = 0; kt < KT; ++kt) {
#pragma unroll
            for (int fb = 0; fb < 4; ++fb) {
                short8 bh = *(const short8*)&Wh[((kt * 4 + fb) * 64 + lane) * 8];
                short8 bl = *(const short8*)&Wl[((kt * 4 + fb) * 64 + lane) * 8];
                acc[fb] = __builtin_amdgcn_mfma_f32_16x16x32_bf16(Ah[kt], bh, acc[fb], 0, 0, 0);
                acc[fb] = __builtin_amdgcn_mfma_f32_16x16x32_bf16(Al[kt], bh, acc[fb], 0, 0, 0);
                acc[fb] = __builtin_amdgcn_mfma_f32_16x16x32_bf16(Ah[kt], bl, acc[fb], 0, 0, 0);
            }
        }

#pragma unroll
        for (int r = 0; r < 4; ++r) {
            int v = v0 + q * 4 + r;
            float pl = 0.f, pr = 0.f;
            bool ok = (v < n);
#pragma unroll
            for (int fb = 0; fb < 4; ++fb) {
                float hv = acc[fb][r];
                if (ok) h16[(size_t)v * 64 + fb * 16 + c] = __float2half(hv);
                pl = fmaf(hv, alv[fb], pl);
                pr = fmaf(hv, arv[fb], pr);
            }
#pragma unroll
            for (int off = 8; off > 0; off >>= 1) {
                pl += __shfl_xor(pl, off);
                pr += __shfl_xor(pr, off);
            }
            if (ok && c == 0) { el[v] = pl; er[v] = pr; }
        }
    }
}

// fused: blocks [0,npb) = partition, [npb, grid) = gemm layer1.
// Disjoint memory: partition writes part/cnts2; gemm writes h16/el/er.
__global__ __launch_bounds__(256) void part_gemm1(
        const int* __restrict__ src, const int* __restrict__ dst, int e,
        int* __restrict__ part, int* __restrict__ cnts2, int nbkt, int npb,
        const float* __restrict__ x, const float* __restrict__ W1,
        const float* __restrict__ al, const float* __restrict__ ar,
        __half* __restrict__ h16, float* __restrict__ el,
        float* __restrict__ er, int n) {
    __shared__ char smem[32768];   // max(partition 12.5KB, gemm 32KB)
    int b = (int)blockIdx.x;
    if (b < npb)
        partition_body(src, dst, e, part, cnts2, nbkt, npb, b, smem);
    else
        gemm_body(x, W1, al, ar, h16, el, er, n, b - npb,
                  (int)gridDim.x - npb, smem);
}

// ---------------- agg layer1 + fused gemm2 epilogue ----------------
// Round-0 agg body (1 node/wave, 16-lane groups, 128B-row gathers) computes
// the relu'd layer-1 row o[64] fully reduced in ALL lanes (xor reductions).
// Epilogue: lane L computes h2[v][L] = sum_k o[k]*W2[k][L] from a 16KB fp32
// LDS copy of W2 (reads W2L[k*64+L]: bank = L&31, 2-way alias = free), plus
// el2/er2 dots. Deletes the separate gemm2 dispatch and the hr round-trip;
// the ~180 extra VALU/LDS ops per node hide under gather latency.
__global__ __launch_bounds__(256) void agg_gemm2(
        const int* __restrict__ row_beg, const int* __restrict__ row_end,
        const int* __restrict__ csr_src, const __half* __restrict__ h16,
        const float* __restrict__ el, const float* __restrict__ er,
        const float* __restrict__ bias1, const float* __restrict__ W2,
        const float* __restrict__ al2, const float* __restrict__ ar2,
        __half* __restrict__ h2out, float* __restrict__ el2,
        float* __restrict__ er2, int n) {
    __shared__ float W2L[4096];   // [k][f] fp32, flat
    for (int i = threadIdx.x; i < 1024; i += 256)
        ((float4*)W2L)[i] = ((const float4*)W2)[i];
    __syncthreads();

    int lane = threadIdx.x & 63;
    int grp = lane >> 4;      // 0..3: edge slot within a 4-edge step
    int c = lane & 15;        // feature quad: features 4c..4c+3
    int gwave = rfl_i((int)((blockIdx.x * blockDim.x + threadIdx.x) >> 6));
    int nwaves = (gridDim.x * blockDim.x) >> 6;
    float4 b4 = ((const float4*)bias1)[c];
    float alv2 = al2[lane], arv2 = ar2[lane];

    for (int v = gwave; v < n; v += nwaves) {
        int rs = rfl_i(row_beg[v]), re = rfl_i(row_end[v]);
        float er_v = er[v];
        float a0 = 0.f, a1 = 0.f, a2 = 0.f, a3 = 0.f, ssum = 0.f;
        for (int base = rs; base < re; base += 64) {
            int cnt = min(64, re - base);
            int s_e = 0;
            float ex = 0.f;
            if (lane < cnt) {
                s_e = csr_src[base + lane];
                float ev = el[s_e] + er_v;
                ev = (ev >= 0.f) ? ev : NEG_SLOPE * ev;
                ex = __expf(ev);
            }
            float cs = ex;
#pragma unroll
            for (int off = 32; off > 0; off >>= 1) cs += __shfl_xor(cs, off);
            ssum += cs;
            int cnt16 = (cnt + 15) & ~15;
            for (int j = 0; j < cnt16; j += 16) {
                int sj[4];
                float exj[4];
                uint2 hv[4];
#pragma unroll
                for (int u = 0; u < 4; ++u) {
                    int idx = j + 4 * u + grp;
                    sj[u] = __shfl(s_e, idx);
                    exj[u] = __shfl(ex, idx);
                    hv[u] = *((const uint2*)(h16 + (size_t)sj[u] * 64) + c);
                }
#pragma unroll
                for (int u = 0; u < 4; ++u) {
                    float2 f01 = __half22float2(*(__half2*)&hv[u].x);
                    float2 f23 = __half22float2(*(__half2*)&hv[u].y);
                    a0 = fmaf(exj[u], f01.x, a0);
                    a1 = fmaf(exj[u], f01.y, a1);
                    a2 = fmaf(exj[u], f23.x, a2);
                    a3 = fmaf(exj[u], f23.y, a3);
                }
            }
        }
        // full reduction -> valid in ALL lanes (lane L holds quad c=L&15)
#pragma unroll
        for (int off = 16; off < 64; off <<= 1) {
            a0 += __shfl_xor(a0, off);
            a1 += __shfl_xor(a1, off);
            a2 += __shfl_xor(a2, off);
            a3 += __shfl_xor(a3, off);
        }
        float4 o;
        if (re > rs) {
            float inv = 1.0f / ssum;
            o.x = fmaf(a0, inv, b4.x);
            o.y = fmaf(a1, inv, b4.y);
            o.z = fmaf(a2, inv, b4.z);
            o.w = fmaf(a3, inv, b4.w);
        } else {
            o = b4;
        }
        o.x = fmaxf(o.x, 0.f);
        o.y = fmaxf(o.y, 0.f);
        o.z = fmaxf(o.z, 0.f);
        o.w = fmaxf(o.w, 0.f);

        // fused gemm2: lane L -> output feature L
        float acc2 = 0.f;
#pragma unroll
        for (int k4 = 0; k4 < 16; ++k4) {
            float vx = __shfl(o.x, k4);
            float vy = __shfl(o.y, k4);
            float vz = __shfl(o.z, k4);
            float vw = __shfl(o.w, k4);
            acc2 = fmaf(vx, W2L[(4 * k4 + 0) * 64 + lane], acc2);
            acc2 = fmaf(vy, W2L[(4 * k4 + 1) * 64 + lane], acc2);
            acc2 = fmaf(vz, W2L[(4 * k4 + 2) * 64 + lane], acc2);
            acc2 = fmaf(vw, W2L[(4 * k4 + 3) * 64 + lane], acc2);
        }
        h2out[(size_t)v * 64 + lane] = __float2half(acc2);
        float pl = acc2 * alv2, pr = acc2 * arv2;
#pragma unroll
        for (int off = 32; off > 0; off >>= 1) {
            pl += __shfl_xor(pl, off);
            pr += __shfl_xor(pr, off);
        }
        if (lane == 0) { el2[v] = pl; er2[v] = pr; }
    }
}

// ---------------- agg layer2 (round-0 proven form, float out) ----------------
__global__ __launch_bounds__(256) void agg_final(
        const int* __restrict__ row_beg, const int* __restrict__ row_end,
        const int* __restrict__ csr_src, const __half* __restrict__ h2,
        const float* __restrict__ el2, const float* __restrict__ er2,
        const float* __restrict__ bias2, float* __restrict__ out, int n) {
    int lane = threadIdx.x & 63;
    int grp = lane >> 4;
    int c = lane & 15;
    int gwave = rfl_i((int)((blockIdx.x * blockDim.x + threadIdx.x) >> 6));
    int nwaves = (gridDim.x * blockDim.x) >> 6;
    float4 b4 = ((const float4*)bias2)[c];
    for (int v = gwave; v < n; v += nwaves) {
        int rs = rfl_i(row_beg[v]), re = rfl_i(row_end[v]);
        float er_v = er2[v];
        float a0 = 0.f, a1 = 0.f, a2 = 0.f, a3 = 0.f, ssum = 0.f;
        for (int base = rs; base < re; base += 64) {
            int cnt = min(64, re - base);
            int s_e = 0;
            float ex = 0.f;
            if (lane < cnt) {
                s_e = csr_src[base + lane];
                float ev = el2[s_e] + er_v;
                ev = (ev >= 0.f) ? ev : NEG_SLOPE * ev;
                ex = __expf(ev);
            }
            float cs = ex;
#pragma unroll
            for (int off = 32; off > 0; off >>= 1) cs += __shfl_xor(cs, off);
            ssum += cs;
            int cnt16 = (cnt + 15) & ~15;
            for (int j = 0; j < cnt16; j += 16) {
                int sj[4];
                float exj[4];
                uint2 hv[4];
#pragma unroll
                for (int u = 0; u < 4; ++u) {
                    int idx = j + 4 * u + grp;
                    sj[u] = __shfl(s_e, idx);
                    exj[u] = __shfl(ex, idx);
                    hv[u] = *((const uint2*)(h2 + (size_t)sj[u] * 64) + c);
                }
#pragma unroll
                for (int u = 0; u < 4; ++u) {
                    float2 f01 = __half22float2(*(__half2*)&hv[u].x);
                    float2 f23 = __half22float2(*(__half2*)&hv[u].y);
                    a0 = fmaf(exj[u], f01.x, a0);
                    a1 = fmaf(exj[u], f01.y, a1);
                    a2 = fmaf(exj[u], f23.x, a2);
                    a3 = fmaf(exj[u], f23.y, a3);
                }
            }
        }
#pragma unroll
        for (int off = 16; off < 64; off <<= 1) {
            a0 += __shfl_xor(a0, off);
            a1 += __shfl_xor(a1, off);
            a2 += __shfl_xor(a2, off);
            a3 += __shfl_xor(a3, off);
        }
        if (lane < 16) {
            float4 o;
            if (re > rs) {
                float inv = 1.0f / ssum;
                o.x = fmaf(a0, inv, b4.x);
                o.y = fmaf(a1, inv, b4.y);
                o.z = fmaf(a2, inv, b4.z);
                o.w = fmaf(a3, inv, b4.w);
            } else {
                o = b4;
            }
            ((float4*)(out + (size_t)v * 64))[c] = o;
        }
    }
}

extern "C" void kernel_launch(void* const* d_in, const int* in_sizes, int n_in,
                              void* d_out, int out_size, void* d_ws, size_t ws_size,
                              hipStream_t stream) {
    (void)n_in; (void)out_size; (void)ws_size;
    const float* features = (const float*)d_in[0];
    // d_in[1] = edge_weights, unused by the reference forward
    const int*   src = (const int*)d_in[2];
    const int*   dst = (const int*)d_in[3];
    const float* W1  = (const float*)d_in[4];
    const float* al1 = (const float*)d_in[5];
    const float* ar1 = (const float*)d_in[6];
    const float* b1  = (const float*)d_in[7];
    const float* W2  = (const float*)d_in[8];
    const float* al2 = (const float*)d_in[9];
    const float* ar2 = (const float*)d_in[10];
    const float* b2  = (const float*)d_in[11];

    const int n = in_sizes[0] / 128;   // 100000
    const int e = in_sizes[2];         // 1600000
    float* out = (float*)d_out;

    char* p = (char*)d_ws;
    auto alloc = [&](size_t bytes) -> char* {
        char* q = p;
        p += (bytes + 255) & ~(size_t)255;
        return q;
    };
    const int nbkt = (n + BKT_SIZE - 1) >> BKT_SHIFT;            // 391
    const int npb  = (e + 256 * P1_EPT - 1) / (256 * P1_EPT);    // 391

    int*    row_beg = (int*)alloc((size_t)n * 4);
    int*    row_end = (int*)alloc((size_t)n * 4);
    int*    csr_src = (int*)alloc((size_t)nbkt * BCAP * 4);      // 9.6MB
    __half* h16     = (__half*)alloc((size_t)n * 64 * 2);
    __half* h2      = (__half*)alloc((size_t)n * 64 * 2);
    float*  el      = (float*)alloc((size_t)n * 4);
    float*  er      = (float*)alloc((size_t)n * 4);
    float*  el2     = (float*)alloc((size_t)n * 4);
    float*  er2     = (float*)alloc((size_t)n * 4);
    int*    cnts2   = (int*)alloc((size_t)nbkt * NPB_PAD * 4);   // 0.6MB
    int*    part    = (int*)alloc((size_t)nbkt * NPB_PAD * SCAP * 4);  // 60MB

    // 4 dispatches, 0 memsets, 0 global atomics.
    part_gemm1<<<npb + 512, 256, 0, stream>>>(src, dst, e, part, cnts2, nbkt, npb,
                                              features, W1, al1, ar1, h16, el, er, n);
    finesort4<<<nbkt, 256, 0, stream>>>(part, cnts2, row_beg, row_end, csr_src,
                                        n, nbkt, npb);
    agg_gemm2<<<4096, 256, 0, stream>>>(row_beg, row_end, csr_src, h16, el, er,
                                        b1, W2, al2, ar2, h2, el2, er2, n);
    agg_final<<<4096, 256, 0, stream>>>(row_beg, row_end, csr_src, h2, el2, er2,
                                        b2, out, n);
}

// Round 7
// 244.029 us; speedup vs baseline: 1.6835x; 1.2715x over previous
//
#include <hip/hip_runtime.h>
#include <hip/hip_fp16.h>
#include <type_traits>

#define NEG_SLOPE 0.2f
#define BKT_SHIFT 8
#define BKT_SIZE (1 << BKT_SHIFT)   // 256 dst nodes per bucket
#define NPB_PAD 400                 // padded partition-block count (npb=391)
#define SCAP 96                     // arena slots per (bucket, block); mean 10.5, +26 sigma
#define BCAP 6144                   // csr window per bucket; mean 4096, +32 sigma
#define P1_EPT 16                   // edges per thread in partition pass

typedef __attribute__((ext_vector_type(8))) short short8;
typedef __attribute__((ext_vector_type(4))) float float4v;

__device__ inline int rfl_i(int v) { return __builtin_amdgcn_readfirstlane(v); }

// round-to-nearest-even fp32 -> bf16
__device__ inline unsigned short f2bf(float f) {
    unsigned u = __float_as_uint(f);
    unsigned r = u + 0x7FFFu + ((u >> 16) & 1u);
    return (unsigned short)(r >> 16);
}
__device__ inline float bf2f(unsigned short b) {
    return __uint_as_float(((unsigned)b) << 16);
}

// ---------------- partition body: fixed (bucket, block) arena slots ----------------
// NO global atomics, NO init required: every cnts2[b][blk] is overwritten.
// Record packed to 4B: src<<8 | (dst & 255)   (src < 2^17 -> 25 bits).
__device__ __forceinline__ void partition_body(
        const int* __restrict__ src, const int* __restrict__ dst, int e,
        int* __restrict__ part, int* __restrict__ cnts2, int nbkt, int npb,
        int blk, char* smem) {
    int (*cnt)[392]    = (int(*)[392])smem;
    int (*base_l)[392] = (int(*)[392])(smem + 4 * 392 * sizeof(int));
    int t = threadIdx.x;
    int wv = t >> 6;
    int cb = blk * (256 * P1_EPT);
    for (int i = t; i < 4 * 392; i += 256) ((int*)cnt)[i] = 0;
    __syncthreads();
    int sr[P1_EPT], ds[P1_EPT], rk[P1_EPT];
#pragma unroll
    for (int i4 = 0; i4 < P1_EPT / 4; ++i4) {
        int eid0 = cb + (i4 * 256 + t) * 4;
        int4 s4, d4;
        bool full = (eid0 + 3 < e);
        if (full) {
            s4 = *(const int4*)(src + eid0);
            d4 = *(const int4*)(dst + eid0);
        }
#pragma unroll
        for (int j = 0; j < 4; ++j) {
            int i = i4 * 4 + j;
            int eid = eid0 + j;
            if (full) {
                sr[i] = (&s4.x)[j];
                ds[i] = (&d4.x)[j];
            } else if (eid < e) {
                sr[i] = src[eid];
                ds[i] = dst[eid];
            }
            rk[i] = (eid < e) ? atomicAdd(&cnt[wv][ds[i] >> BKT_SHIFT], 1) : -1;
        }
    }
    __syncthreads();
    // per-bucket wave prefixes (offset within this block's fixed slot) + count
    for (int b = t; b < nbkt; b += 256) {
        int c0 = cnt[0][b], c1 = cnt[1][b], c2 = cnt[2][b], c3 = cnt[3][b];
        int tot = c0 + c1 + c2 + c3;
        base_l[0][b] = 0;
        base_l[1][b] = c0;
        base_l[2][b] = c0 + c1;
        base_l[3][b] = c0 + c1 + c2;
        cnts2[b * NPB_PAD + blk] = min(tot, SCAP);   // ALWAYS written (no init)
    }
    __syncthreads();
#pragma unroll
    for (int i = 0; i < P1_EPT; ++i) {
        if (rk[i] >= 0) {
            int b = ds[i] >> BKT_SHIFT;
            int o = base_l[wv][b] + rk[i];
            if (o < SCAP)   // safety clamp (P ~ 0)
                part[((size_t)b * NPB_PAD + blk) * SCAP + o] =
                    (sr[i] << BKT_SHIFT) | (ds[i] & (BKT_SIZE - 1));
        }
    }
}

// ---------------- finesort4: bucket-independent, LDS-staged, atomic-free io ----------------
// Bucket b owns csr window [b*BCAP, ...). Stages its ~4096 records into LDS
// once, counts, scans, writes row_beg/row_end and scatters. No cross-bucket
// dependency, no global atomics.
__global__ __launch_bounds__(256) void finesort4(
        const int* __restrict__ part, const int* __restrict__ cnts2,
        int* __restrict__ row_beg, int* __restrict__ row_end,
        int* __restrict__ csr_src, int n, int nbkt, int npb) {
    __shared__ int cnt[256];
    __shared__ int cur[256];
    __shared__ int tmp[256];
    __shared__ int stage[BCAP];   // 24KB
    int b = blockIdx.x, t = threadIdx.x;
    // per-partition-block counts for blks 2t, 2t+1 -> exclusive prefix
    int blk0 = 2 * t, blk1 = 2 * t + 1;
    int c0 = (blk0 < npb) ? cnts2[b * NPB_PAD + blk0] : 0;
    int c1 = (blk1 < npb) ? cnts2[b * NPB_PAD + blk1] : 0;
    int s = c0 + c1;
    tmp[t] = s;
    __syncthreads();
    for (int o = 1; o < 256; o <<= 1) {
        int x = tmp[t];
        int y = (t >= o) ? tmp[t - o] : 0;
        __syncthreads();
        tmp[t] = x + y;
        __syncthreads();
    }
    int excl = tmp[t] - s;
    int S = tmp[255];
    int Seff = min(S, BCAP);
    // stage the two runs this thread owns
    {
        const int* sp0 = part + ((size_t)b * NPB_PAD + blk0) * SCAP;
        for (int i = 0; i < c0; ++i) {
            int p = excl + i;
            if (p < BCAP) stage[p] = sp0[i];
        }
        const int* sp1 = part + ((size_t)b * NPB_PAD + blk1) * SCAP;
        int sb1 = excl + c0;
        for (int i = 0; i < c1; ++i) {
            int p = sb1 + i;
            if (p < BCAP) stage[p] = sp1[i];
        }
    }
    cnt[t] = 0;
    __syncthreads();   // fences stage writes + cnt zeroing
    for (int i = t; i < Seff; i += 256)
        atomicAdd(&cnt[stage[i] & (BKT_SIZE - 1)], 1);
    __syncthreads();
    int d0 = b << BKT_SHIFT;
    int nloc = min(BKT_SIZE, n - d0);
    int c = cnt[t];
    tmp[t] = c;
    __syncthreads();
    for (int o = 1; o < 256; o <<= 1) {
        int x = tmp[t];
        int y = (t >= o) ? tmp[t - o] : 0;
        __syncthreads();
        tmp[t] = x + y;
        __syncthreads();
    }
    int pos0 = b * BCAP + tmp[t] - c;
    cur[t] = pos0;
    if (t < nloc) {
        row_beg[d0 + t] = pos0;
        row_end[d0 + t] = pos0 + c;
    }
    __syncthreads();
    for (int i = t; i < Seff; i += 256) {
        int pk = stage[i];
        int pos = atomicAdd(&cur[pk & (BKT_SIZE - 1)], 1);
        csr_src[pos] = ((unsigned)pk) >> BKT_SHIFT;
    }
}

// ---------------- MFMA GEMM body (in-kernel W decomposition) ----------------
// h[N,64] fp16 row-major = x[N,K] @ W[K,64] via v_mfma_f32_16x16x32_bf16,
// bf16x3 split; also el/er attention dots.
// IN = float (layer1) or __half (layer2; fp16 splits into bf16 hi+lo exactly).
template <int KT, typename IN>
__device__ __forceinline__ void gemm_body(
        const IN* __restrict__ x, const float* __restrict__ W,
        const float* __restrict__ al, const float* __restrict__ ar,
        __half* __restrict__ h16, float* __restrict__ el,
        float* __restrict__ er, int n, int bid, int nblocks, char* smem) {
    constexpr int K = KT * 32;
    constexpr int WFRAG = KT * 4 * 64 * 8;   // shorts
    unsigned short* Wh = (unsigned short*)smem;
    unsigned short* Wl = Wh + WFRAG;
    for (int idx = threadIdx.x; idx < KT * 4 * 64; idx += 256) {
        int lane = idx & 63, fbkt = idx >> 6;
        int fb = fbkt & 3, kt = fbkt >> 2;
        int q = lane >> 4, c = lane & 15;
#pragma unroll
        for (int j = 0; j < 8; ++j) {
            float w = W[(kt * 32 + q * 8 + j) * 64 + fb * 16 + c];
            unsigned short hi = f2bf(w);
            Wh[idx * 8 + j] = hi;
            Wl[idx * 8 + j] = f2bf(w - bf2f(hi));
        }
    }
    __syncthreads();

    int lane = threadIdx.x & 63;
    int q = lane >> 4, c = lane & 15;
    int wave = bid * 4 + (int)(threadIdx.x >> 6);
    int nwaves = nblocks * 4;
    int ntiles = (n + 15) >> 4;

    float alv[4], arv[4];
#pragma unroll
    for (int fb = 0; fb < 4; ++fb) {
        alv[fb] = al[fb * 16 + c];
        arv[fb] = ar[fb * 16 + c];
    }

    for (int t = wave; t < ntiles; t += nwaves) {
        int v0 = t * 16;
        int row = min(v0 + c, n - 1);
        const IN* xr = x + (size_t)row * K + q * 8;

        short8 Ah[KT], Al[KT];
#pragma unroll
        for (int kt = 0; kt < KT; ++kt) {
            float xv[8];
            if constexpr (std::is_same<IN, float>::value) {
                *(float4*)&xv[0] = *(const float4*)(xr + kt * 32);
                *(float4*)&xv[4] = *(const float4*)(xr + kt * 32 + 4);
            } else {
                __half hh[8];
                *(uint4*)hh = *(const uint4*)(xr + kt * 32);
#pragma unroll
                for (int j = 0; j < 8; ++j) xv[j] = __half2float(hh[j]);
            }
#pragma unroll
            for (int j = 0; j < 8; ++j) {
                unsigned short hi = f2bf(xv[j]);
                Ah[kt][j] = (short)hi;
                Al[kt][j] = (short)f2bf(xv[j] - bf2f(hi));
            }
        }

        float4v acc[4];
#pragma unroll
        for (int fb = 0; fb < 4; ++fb) acc[fb] = (float4v)0.f;

#pragma unroll
        for (int kt = 0; kt < KT; ++kt) {
#pragma unroll
            for (int fb = 0; fb < 4; ++fb) {
                short8 bh = *(const short8*)&Wh[((kt * 4 + fb) * 64 + lane) * 8];
                short8 bl = *(const short8*)&Wl[((kt * 4 + fb) * 64 + lane) * 8];
                acc[fb] = __builtin_amdgcn_mfma_f32_16x16x32_bf16(Ah[kt], bh, acc[fb], 0, 0, 0);
                acc[fb] = __builtin_amdgcn_mfma_f32_16x16x32_bf16(Al[kt], bh, acc[fb], 0, 0, 0);
                acc[fb] = __builtin_amdgcn_mfma_f32_16x16x32_bf16(Ah[kt], bl, acc[fb], 0, 0, 0);
            }
        }

#pragma unroll
        for (int r = 0; r < 4; ++r) {
            int v = v0 + q * 4 + r;
            float pl = 0.f, pr = 0.f;
            bool ok = (v < n);
#pragma unroll
            for (int fb = 0; fb < 4; ++fb) {
                float hv = acc[fb][r];
                if (ok) h16[(size_t)v * 64 + fb * 16 + c] = __float2half(hv);
                pl = fmaf(hv, alv[fb], pl);
                pr = fmaf(hv, arv[fb], pr);
            }
#pragma unroll
            for (int off = 8; off > 0; off >>= 1) {
                pl += __shfl_xor(pl, off);
                pr += __shfl_xor(pr, off);
            }
            if (ok && c == 0) { el[v] = pl; er[v] = pr; }
        }
    }
}

// fused: blocks [0,npb) = partition, [npb, grid) = gemm layer1.
// Disjoint memory: partition writes part/cnts2; gemm writes h16/el/er.
__global__ __launch_bounds__(256) void part_gemm1(
        const int* __restrict__ src, const int* __restrict__ dst, int e,
        int* __restrict__ part, int* __restrict__ cnts2, int nbkt, int npb,
        const float* __restrict__ x, const float* __restrict__ W1,
        const float* __restrict__ al, const float* __restrict__ ar,
        __half* __restrict__ h16, float* __restrict__ el,
        float* __restrict__ er, int n) {
    __shared__ char smem[32768];   // max(partition 12.5KB, gemm KT=4 32KB)
    int b = (int)blockIdx.x;
    if (b < npb)
        partition_body(src, dst, e, part, cnts2, nbkt, npb, b, smem);
    else
        gemm_body<4, float>(x, W1, al, ar, h16, el, er, n, b - npb,
                            (int)gridDim.x - npb, smem);
}

template <int KT, typename IN>
__global__ __launch_bounds__(256) void gemm_mfma_kernel(
        const IN* __restrict__ x, const float* __restrict__ W,
        const float* __restrict__ al, const float* __restrict__ ar,
        __half* __restrict__ h16, float* __restrict__ el,
        float* __restrict__ er, int n) {
    __shared__ char smem[KT * 4 * 64 * 8 * 2 * 2];
    gemm_body<KT, IN>(x, W, al, ar, h16, el, er, n, (int)blockIdx.x,
                      (int)gridDim.x, smem);
}

// ---------------- softmax-aggregate (round-0 proven form) ----------------
// 1 node/wave; 4 edges per step (16-lane groups, uint2 = 4 fp16 feats/lane).
// OUT = __half (layer1: relu'd hr) or float (layer2: d_out).
template <typename OUT>
__global__ __launch_bounds__(256) void agg_kernel(
        const int* __restrict__ row_beg, const int* __restrict__ row_end,
        const int* __restrict__ csr_src, const __half* __restrict__ h16,
        const float* __restrict__ el, const float* __restrict__ er,
        const float* __restrict__ bias, OUT* __restrict__ out,
        int n, int do_relu) {
    int lane = threadIdx.x & 63;
    int grp = lane >> 4;      // 0..3: edge slot within a 4-edge step
    int c = lane & 15;        // feature quad: features 4c..4c+3
    int gwave = rfl_i((int)((blockIdx.x * blockDim.x + threadIdx.x) >> 6));
    int nwaves = (gridDim.x * blockDim.x) >> 6;
    float4 b4 = ((const float4*)bias)[c];
    for (int v = gwave; v < n; v += nwaves) {
        int rs = rfl_i(row_beg[v]), re = rfl_i(row_end[v]);
        float er_v = er[v];
        float a0 = 0.f, a1 = 0.f, a2 = 0.f, a3 = 0.f, ssum = 0.f;
        for (int base = rs; base < re; base += 64) {
            int cnt = min(64, re - base);
            int s_e = 0;
            float ex = 0.f;
            if (lane < cnt) {
                s_e = csr_src[base + lane];
                float ev = el[s_e] + er_v;
                ev = (ev >= 0.f) ? ev : NEG_SLOPE * ev;
                ex = __expf(ev);
            }
            float cs = ex;
#pragma unroll
            for (int off = 32; off > 0; off >>= 1) cs += __shfl_xor(cs, off);
            ssum += cs;
            int cnt16 = (cnt + 15) & ~15;
            for (int j = 0; j < cnt16; j += 16) {
                int sj[4];
                float exj[4];
                uint2 hv[4];
#pragma unroll
                for (int u = 0; u < 4; ++u) {
                    int idx = j + 4 * u + grp;
                    sj[u] = __shfl(s_e, idx);
                    exj[u] = __shfl(ex, idx);
                    hv[u] = *((const uint2*)(h16 + (size_t)sj[u] * 64) + c);
                }
#pragma unroll
                for (int u = 0; u < 4; ++u) {
                    float2 f01 = __half22float2(*(__half2*)&hv[u].x);
                    float2 f23 = __half22float2(*(__half2*)&hv[u].y);
                    a0 = fmaf(exj[u], f01.x, a0);
                    a1 = fmaf(exj[u], f01.y, a1);
                    a2 = fmaf(exj[u], f23.x, a2);
                    a3 = fmaf(exj[u], f23.y, a3);
                }
            }
        }
        // combine the 4 edge-groups: reduce over lane bits 4,5
#pragma unroll
        for (int off = 16; off < 64; off <<= 1) {
            a0 += __shfl_xor(a0, off);
            a1 += __shfl_xor(a1, off);
            a2 += __shfl_xor(a2, off);
            a3 += __shfl_xor(a3, off);
        }
        if (lane < 16) {
            float4 o;
            if (re > rs) {
                float inv = 1.0f / ssum;
                o.x = fmaf(a0, inv, b4.x);
                o.y = fmaf(a1, inv, b4.y);
                o.z = fmaf(a2, inv, b4.z);
                o.w = fmaf(a3, inv, b4.w);
            } else {
                o = b4;
            }
            if (do_relu) {
                o.x = fmaxf(o.x, 0.f);
                o.y = fmaxf(o.y, 0.f);
                o.z = fmaxf(o.z, 0.f);
                o.w = fmaxf(o.w, 0.f);
            }
            if constexpr (std::is_same<OUT, __half>::value) {
                uint2 pk;
                *(__half2*)&pk.x = __float22half2_rn(make_float2(o.x, o.y));
                *(__half2*)&pk.y = __float22half2_rn(make_float2(o.z, o.w));
                ((uint2*)(out + (size_t)v * 64))[c] = pk;
            } else {
                ((float4*)(out + (size_t)v * 64))[c] = o;
            }
        }
    }
}

extern "C" void kernel_launch(void* const* d_in, const int* in_sizes, int n_in,
                              void* d_out, int out_size, void* d_ws, size_t ws_size,
                              hipStream_t stream) {
    (void)n_in; (void)out_size; (void)ws_size;
    const float* features = (const float*)d_in[0];
    // d_in[1] = edge_weights, unused by the reference forward
    const int*   src = (const int*)d_in[2];
    const int*   dst = (const int*)d_in[3];
    const float* W1  = (const float*)d_in[4];
    const float* al1 = (const float*)d_in[5];
    const float* ar1 = (const float*)d_in[6];
    const float* b1  = (const float*)d_in[7];
    const float* W2  = (const float*)d_in[8];
    const float* al2 = (const float*)d_in[9];
    const float* ar2 = (const float*)d_in[10];
    const float* b2  = (const float*)d_in[11];

    const int n = in_sizes[0] / 128;   // 100000
    const int e = in_sizes[2];         // 1600000
    float* out = (float*)d_out;

    char* p = (char*)d_ws;
    auto alloc = [&](size_t bytes) -> char* {
        char* q = p;
        p += (bytes + 255) & ~(size_t)255;
        return q;
    };
    const int nbkt = (n + BKT_SIZE - 1) >> BKT_SHIFT;            // 391
    const int npb  = (e + 256 * P1_EPT - 1) / (256 * P1_EPT);    // 391

    int*    row_beg = (int*)alloc((size_t)n * 4);
    int*    row_end = (int*)alloc((size_t)n * 4);
    int*    csr_src = (int*)alloc((size_t)nbkt * BCAP * 4);      // 9.6MB
    __half* h16     = (__half*)alloc((size_t)n * 64 * 2);
    __half* hr      = (__half*)alloc((size_t)n * 64 * 2);
    float*  el      = (float*)alloc((size_t)n * 4);
    float*  er      = (float*)alloc((size_t)n * 4);
    int*    cnts2   = (int*)alloc((size_t)nbkt * NPB_PAD * 4);   // 0.6MB
    int*    part    = (int*)alloc((size_t)nbkt * NPB_PAD * SCAP * 4);  // 60MB

    // 5 dispatches, 0 memsets, 0 global atomics.
    // CSR build (atomic-free) fused with gemm1 (independent memory).
    part_gemm1<<<npb + 512, 256, 0, stream>>>(src, dst, e, part, cnts2, nbkt, npb,
                                              features, W1, al1, ar1, h16, el, er, n);
    finesort4<<<nbkt, 256, 0, stream>>>(part, cnts2, row_beg, row_end, csr_src,
                                        n, nbkt, npb);

    // layer 1 aggregate -> hr (fp16 row-major)
    agg_kernel<__half><<<4096, 256, 0, stream>>>(row_beg, row_end, csr_src, h16,
                                                 el, er, b1, hr, n, 1);
    // layer 2 GEMM (overwrites h16/el/er) + aggregate -> out
    gemm_mfma_kernel<2, __half><<<512, 256, 0, stream>>>(hr, W2, al2, ar2,
                                                         h16, el, er, n);
    agg_kernel<float><<<4096, 256, 0, stream>>>(row_beg, row_end, csr_src, h16,
                                                el, er, b2, out, n, 0);
}